// Round 4
// baseline (47.151 us; speedup 1.0000x reference)
//
#include <hip/hip_runtime.h>
#include <math.h>

// QuantumGenerator fused single kernel.
// out_j(x) = sum_{p in {I,Z,Y}^4} D_j[p] * prod_w f_{p_w}(x_w),  f = (1, cos, -sin).
// Phase A (per block, redundant): build the 81x4 coefficient table D in LDS
//   (shfl-parallel 16x16 unitary build; bias folded into all-I term).
// Phase B: E=4 elements/thread, named float4 registers (components = elements),
//   uniform ds_read_b128 broadcasts of D, signs folded into FMA neg-modifiers.

__device__ __forceinline__ float4 mul4(const float4 a, const float4 b) {
  return make_float4(a.x*b.x, a.y*b.y, a.z*b.z, a.w*b.w);
}
// h += s * g   (scalar coefficient, vector-over-elements g)
__device__ __forceinline__ float4 fma4p(float s, const float4 g, float4 h) {
  h.x = fmaf(s, g.x, h.x); h.y = fmaf(s, g.y, h.y);
  h.z = fmaf(s, g.z, h.z); h.w = fmaf(s, g.w, h.w);
  return h;
}
// h += s * (-g)
__device__ __forceinline__ float4 fma4n(float s, const float4 g, float4 h) {
  h.x = fmaf(s, -g.x, h.x); h.y = fmaf(s, -g.y, h.y);
  h.z = fmaf(s, -g.z, h.z); h.w = fmaf(s, -g.w, h.w);
  return h;
}
// a += g .* h  (elementwise)
__device__ __forceinline__ float4 fma4v(const float4 g, const float4 h, float4 a) {
  a.x = fmaf(g.x, h.x, a.x); a.y = fmaf(g.y, h.y, a.y);
  a.z = fmaf(g.z, h.z, a.z); a.w = fmaf(g.w, h.w, a.w);
  return a;
}
// a += (-g) .* h
__device__ __forceinline__ float4 fma4vn(const float4 g, const float4 h, float4 a) {
  a.x = fmaf(-g.x, h.x, a.x); a.y = fmaf(-g.y, h.y, a.y);
  a.z = fmaf(-g.z, h.z, a.z); a.w = fmaf(-g.w, h.w, a.w);
  return a;
}

__global__ __launch_bounds__(256) void qg_fused(
    const float4* __restrict__ noise,   // [B] float4 (x0..x3)
    const float*  __restrict__ qw,      // [2][4][3]
    const float*  __restrict__ Wm,      // [4][4]
    const float*  __restrict__ bv,      // [4]
    float4* __restrict__ out,           // [B] float4
    int B)
{
  __shared__ float  gm[24][8];
  __shared__ float2 Ul[16][16];
  __shared__ float  wj[4][16];
  __shared__ float2 A[4][16][16];
  __shared__ float4 Dl[81];
  const int tid = threadIdx.x;

  // ======== Phase A: build D table in LDS ========
  if (tid < 24) {
    const float phi = qw[tid*3 + 0];
    const float th  = qw[tid*3 + 1];
    const float om  = qw[tid*3 + 2];
    float st, ct, sa, ca, sd, cd;
    __sincosf(0.5f*th,       &st, &ct);
    __sincosf(0.5f*(phi+om), &sa, &ca);
    __sincosf(0.5f*(phi-om), &sd, &cd);
    gm[tid][0] =  ca*ct; gm[tid][1] = -sa*ct;
    gm[tid][2] = -cd*st; gm[tid][3] = -sd*st;
    gm[tid][4] =  cd*st; gm[tid][5] = -sd*st;
    gm[tid][6] =  ca*ct; gm[tid][7] =  sa*ct;
  }
  if (tid >= 192) {
    const int j = (tid - 192) >> 4, k = tid & 15;
    float s = 0.f;
    #pragma unroll
    for (int i = 0; i < 4; ++i)
      s += Wm[j*4 + i] * (((k >> (3 - i)) & 1) ? -1.f : 1.f);
    wj[j][k] = s;
  }
  __syncthreads();

  {  // U build: one matrix element per thread, shfl butterflies (within 16-lane groups)
    const int col = tid >> 4, row = tid & 15;
    float vr = (row == col) ? 1.f : 0.f, vi = 0.f;
    #pragma unroll
    for (int l = 0; l < 2; ++l) {
      #pragma unroll
      for (int w = 0; w < 4; ++w) {
        const int g = l*4 + w;
        const float m00r = gm[g][0], m00i = gm[g][1];
        const float m01r = gm[g][2], m01i = gm[g][3];
        const float m10r = gm[g][4], m10i = gm[g][5];
        const float m11r = gm[g][6], m11i = gm[g][7];
        const int mask = 8 >> w;
        const float pr = __shfl_xor(vr, mask);
        const float pi = __shfl_xor(vi, mask);
        float nr, ni;
        if (!(row & mask)) {
          nr = m00r*vr - m00i*vi + m01r*pr - m01i*pi;
          ni = m00r*vi + m00i*vr + m01r*pi + m01i*pr;
        } else {
          nr = m10r*pr - m10i*pi + m11r*vr - m11i*vi;
          ni = m10r*pi + m10i*pr + m11r*vi + m11i*vr;
        }
        vr = nr; vi = ni;
      }
      const int r = l + 1;  // StronglyEntanglingLayers ranges for 2 layers
      #pragma unroll
      for (int w = 0; w < 4; ++w) {
        const int t  = (w + r) & 3;
        const int cm = 8 >> w, tm = 8 >> t;
        const float pr = __shfl_xor(vr, tm);
        const float pi = __shfl_xor(vi, tm);
        if (row & cm) { vr = pr; vi = pi; }
      }
    }
    Ul[row][col] = make_float2(vr, vi);
  }
  __syncthreads();

  {  // A[j][s][t] = sum_k conj(U[k][s]) wj[j][k] U[k][t]
    const int s = tid >> 4, t = tid & 15;
    float ar[4] = {0,0,0,0}, ai[4] = {0,0,0,0};
    #pragma unroll
    for (int k = 0; k < 16; ++k) {
      const float2 us = Ul[k][s], ut = Ul[k][t];
      const float pr = us.x*ut.x + us.y*ut.y;
      const float pi = us.x*ut.y - us.y*ut.x;
      #pragma unroll
      for (int j = 0; j < 4; ++j) { ar[j] += wj[j][k]*pr; ai[j] += wj[j][k]*pi; }
    }
    #pragma unroll
    for (int j = 0; j < 4; ++j) A[j][s][t] = make_float2(ar[j], ai[j]);
  }
  __syncthreads();

  // D_j[p] = (1/16) Tr(A_j sigma_p), sigma in {I,Z,Y}^4, stored Dl[p].j
  for (int item = tid; item < 324; item += 256) {
    const int j = item / 81, p = item % 81;
    const int p1 = p / 27, p2 = (p / 9) % 3, p3 = (p / 3) % 3, p4 = p % 3;
    int ym = 0, ny = 0;
    if (p1 == 2) { ym |= 8; ++ny; }
    if (p2 == 2) { ym |= 4; ++ny; }
    if (p3 == 2) { ym |= 2; ++ny; }
    if (p4 == 2) { ym |= 1; ++ny; }
    float sum = 0.f;
    for (int t = 0; t < 16; ++t) {
      const int t0 = (t>>3)&1, t1 = (t>>2)&1, t2 = (t>>1)&1, t3 = t&1;
      float sgn = 1.f;
      if      (p1 == 1) sgn *= t0 ? -1.f : 1.f;
      else if (p1 == 2) sgn *= t0 ?  1.f : -1.f;
      if      (p2 == 1) sgn *= t1 ? -1.f : 1.f;
      else if (p2 == 2) sgn *= t1 ?  1.f : -1.f;
      if      (p3 == 1) sgn *= t2 ? -1.f : 1.f;
      else if (p3 == 2) sgn *= t2 ?  1.f : -1.f;
      if      (p4 == 1) sgn *= t3 ? -1.f : 1.f;
      else if (p4 == 2) sgn *= t3 ?  1.f : -1.f;
      const float2 ae = A[j][t ^ ym][t];
      const int m = ny & 3;
      const float re = (m == 0) ? ae.x : (m == 1) ? -ae.y : (m == 2) ? -ae.x : ae.y;
      sum += sgn * re;
    }
    sum *= 0.0625f;
    if (p == 0) sum += bv[j];
    ((float*)&Dl[p])[j] = sum;
  }
  __syncthreads();

  // ======== Phase B: E=4 elements per thread ========
  const int base = blockIdx.x * 1024 + tid;   // elems: base + {0,256,512,768}
  const int Bm1 = B - 1;
  const float4 xa = noise[min(base,        Bm1)];
  const float4 xb = noise[min(base +  256, Bm1)];
  const float4 xc = noise[min(base +  512, Bm1)];
  const float4 xd = noise[min(base +  768, Bm1)];

  float sA0,cA0,sA1,cA1,sA2,cA2,sA3,cA3;
  float sB0,cB0,sB1,cB1,sB2,cB2,sB3,cB3;
  float sC0,cC0,sC1,cC1,sC2,cC2,sC3,cC3;
  float sD0,cD0,sD1,cD1,sD2,cD2,sD3,cD3;
  __sincosf(xa.x,&sA0,&cA0); __sincosf(xa.y,&sA1,&cA1); __sincosf(xa.z,&sA2,&cA2); __sincosf(xa.w,&sA3,&cA3);
  __sincosf(xb.x,&sB0,&cB0); __sincosf(xb.y,&sB1,&cB1); __sincosf(xb.z,&sB2,&cB2); __sincosf(xb.w,&sB3,&cB3);
  __sincosf(xc.x,&sC0,&cC0); __sincosf(xc.y,&sC1,&cC1); __sincosf(xc.z,&sC2,&cC2); __sincosf(xc.w,&sC3,&cC3);
  __sincosf(xd.x,&sD0,&cD0); __sincosf(xd.y,&sD1,&cD1); __sincosf(xd.z,&sD2,&cD2); __sincosf(xd.w,&sD3,&cD3);

  const float4 c0v = make_float4(cA0,cB0,cC0,cD0), s0v = make_float4(sA0,sB0,sC0,sD0);
  const float4 c1v = make_float4(cA1,cB1,cC1,cD1), s1v = make_float4(sA1,sB1,sC1,sD1);
  const float4 c2v = make_float4(cA2,cB2,cC2,cD2), s2v = make_float4(sA2,sB2,sC2,sD2);
  const float4 c3v = make_float4(cA3,cB3,cC3,cD3), s3v = make_float4(sA3,sB3,sC3,sD3);
  const float4 c2c3 = mul4(c2v,c3v), c2s3 = mul4(c2v,s3v);
  const float4 s2c3 = mul4(s2v,c3v), s2s3 = mul4(s2v,s3v);
  const float4 c0c1 = mul4(c0v,c1v), c0s1 = mul4(c0v,s1v);
  const float4 s0c1 = mul4(s0v,c1v), s0s1 = mul4(s0v,s1v);

  float4 h0, h1, h2, h3, acc0, acc1, acc2, acc3;

  // g34[b] = f3[b/3]*f4[b%3], f = (1, cos, -sin); signs folded via fma4p/fma4n
#define HT(a,b,FN,G) { const float4 q = Dl[(a)*9+(b)];          \
    h0 = FN(q.x, G, h0); h1 = FN(q.y, G, h1);                   \
    h2 = FN(q.z, G, h2); h3 = FN(q.w, G, h3); }
#define HB(a) { const float4 q = Dl[(a)*9];                     \
    h0 = make_float4(q.x,q.x,q.x,q.x); h1 = make_float4(q.y,q.y,q.y,q.y); \
    h2 = make_float4(q.z,q.z,q.z,q.z); h3 = make_float4(q.w,q.w,q.w,q.w); } \
    HT(a,1,fma4p,c3v)  HT(a,2,fma4n,s3v)  HT(a,3,fma4p,c2v)     \
    HT(a,4,fma4p,c2c3) HT(a,5,fma4n,c2s3) HT(a,6,fma4n,s2v)     \
    HT(a,7,fma4n,s2c3) HT(a,8,fma4p,s2s3)
#define ACC(FN,G) { acc0 = FN(G,h0,acc0); acc1 = FN(G,h1,acc1); \
                    acc2 = FN(G,h2,acc2); acc3 = FN(G,h3,acc3); }

  HB(0) acc0 = h0; acc1 = h1; acc2 = h2; acc3 = h3;
  HB(1) ACC(fma4v,  c1v)
  HB(2) ACC(fma4vn, s1v)
  HB(3) ACC(fma4v,  c0v)
  HB(4) ACC(fma4v,  c0c1)
  HB(5) ACC(fma4vn, c0s1)
  HB(6) ACC(fma4vn, s0v)
  HB(7) ACC(fma4vn, s0c1)
  HB(8) ACC(fma4v,  s0s1)

#undef HT
#undef HB
#undef ACC

  if (base < B)
    out[base]       = make_float4(fabsf(acc0.x) + 0.001f, acc1.x, acc2.x, acc3.x);
  if (base + 256 < B)
    out[base + 256] = make_float4(fabsf(acc0.y) + 0.001f, acc1.y, acc2.y, acc3.y);
  if (base + 512 < B)
    out[base + 512] = make_float4(fabsf(acc0.z) + 0.001f, acc1.z, acc2.z, acc3.z);
  if (base + 768 < B)
    out[base + 768] = make_float4(fabsf(acc0.w) + 0.001f, acc1.w, acc2.w, acc3.w);
}

extern "C" void kernel_launch(void* const* d_in, const int* in_sizes, int n_in,
                              void* d_out, int out_size, void* d_ws, size_t ws_size,
                              hipStream_t stream) {
  const float* noise = (const float*)d_in[0];   // [B,4]
  const float* qw    = (const float*)d_in[1];   // [2,4,3]
  const float* Wm    = (const float*)d_in[2];   // [4,4]
  const float* bv    = (const float*)d_in[3];   // [4]
  const int B = in_sizes[0] / 4;

  const int blocks = (B + 1023) / 1024;
  hipLaunchKernelGGL(qg_fused, dim3(blocks), dim3(256), 0, stream,
                     (const float4*)noise, qw, Wm, bv, (float4*)d_out, B);
}

// Round 5
// 24.891 us; speedup vs baseline: 1.8943x; 1.8943x over previous
//
#include <hip/hip_runtime.h>
#include <math.h>

// QuantumGenerator: 4-qubit, 2-layer StronglyEntanglingLayers circuit + Linear(4,4).
// out_j(x) = sum_{p in {I,Z,Y}^4} D_j[p] * prod_w f_{p_w}(x_w),  f = (1, cos, -sin).
// qg_precompute (1 block, parallel): builds the 81x4 coefficient table D
//   (shfl-distributed 16x16 unitary build, fast __sincosf; bias folded into all-I).
// qg_main (E=1): all-named-scalar body, D read as uniform float4 (81 loads).

__global__ __launch_bounds__(256) void qg_precompute(
    const float* __restrict__ qw,   // [2][4][3] (phi, theta, omega)
    const float* __restrict__ Wm,   // [4][4]
    const float* __restrict__ bv,   // [4]
    float* __restrict__ Dcoef)      // [81][4]
{
  __shared__ float  gm[24][8];      // per-gate 2x2 complex matrix
  __shared__ float2 Ul[16][16];     // U[k][col]
  __shared__ float  wj[4][16];
  __shared__ float2 A[4][16][16];
  const int tid = threadIdx.x;

  if (tid < 24) {
    const float phi = qw[tid*3 + 0];
    const float th  = qw[tid*3 + 1];
    const float om  = qw[tid*3 + 2];
    float st, ct, sa, ca, sd, cd;
    __sincosf(0.5f*th,       &st, &ct);
    __sincosf(0.5f*(phi+om), &sa, &ca);
    __sincosf(0.5f*(phi-om), &sd, &cd);
    gm[tid][0] =  ca*ct; gm[tid][1] = -sa*ct;   // m00
    gm[tid][2] = -cd*st; gm[tid][3] = -sd*st;   // m01
    gm[tid][4] =  cd*st; gm[tid][5] = -sd*st;   // m10
    gm[tid][6] =  ca*ct; gm[tid][7] =  sa*ct;   // m11
  }
  if (tid >= 192) {
    const int j = (tid - 192) >> 4, k = tid & 15;
    float s = 0.f;
    #pragma unroll
    for (int i = 0; i < 4; ++i)
      s += Wm[j*4 + i] * (((k >> (3 - i)) & 1) ? -1.f : 1.f);
    wj[j][k] = s;
  }
  __syncthreads();

  {  // U build: one matrix element per thread, shfl butterflies (16-lane groups)
    const int col = tid >> 4, row = tid & 15;
    float vr = (row == col) ? 1.f : 0.f, vi = 0.f;
    #pragma unroll
    for (int l = 0; l < 2; ++l) {
      #pragma unroll
      for (int w = 0; w < 4; ++w) {
        const int g = l*4 + w;
        const float m00r = gm[g][0], m00i = gm[g][1];
        const float m01r = gm[g][2], m01i = gm[g][3];
        const float m10r = gm[g][4], m10i = gm[g][5];
        const float m11r = gm[g][6], m11i = gm[g][7];
        const int mask = 8 >> w;
        const float pr = __shfl_xor(vr, mask);
        const float pi = __shfl_xor(vi, mask);
        float nr, ni;
        if (!(row & mask)) {
          nr = m00r*vr - m00i*vi + m01r*pr - m01i*pi;
          ni = m00r*vi + m00i*vr + m01r*pi + m01i*pr;
        } else {
          nr = m10r*pr - m10i*pi + m11r*vr - m11i*vi;
          ni = m10r*pi + m10i*pr + m11r*vi + m11i*vr;
        }
        vr = nr; vi = ni;
      }
      const int r = l + 1;  // StronglyEntanglingLayers ranges for 2 layers
      #pragma unroll
      for (int w = 0; w < 4; ++w) {
        const int t  = (w + r) & 3;
        const int cm = 8 >> w, tm = 8 >> t;
        const float pr = __shfl_xor(vr, tm);
        const float pi = __shfl_xor(vi, tm);
        if (row & cm) { vr = pr; vi = pi; }
      }
    }
    Ul[row][col] = make_float2(vr, vi);
  }
  __syncthreads();

  {  // A[j][s][t] = sum_k conj(U[k][s]) wj[j][k] U[k][t]
    const int s = tid >> 4, t = tid & 15;
    float ar[4] = {0,0,0,0}, ai[4] = {0,0,0,0};
    #pragma unroll
    for (int k = 0; k < 16; ++k) {
      const float2 us = Ul[k][s], ut = Ul[k][t];
      const float pr = us.x*ut.x + us.y*ut.y;
      const float pi = us.x*ut.y - us.y*ut.x;
      #pragma unroll
      for (int j = 0; j < 4; ++j) { ar[j] += wj[j][k]*pr; ai[j] += wj[j][k]*pi; }
    }
    #pragma unroll
    for (int j = 0; j < 4; ++j) A[j][s][t] = make_float2(ar[j], ai[j]);
  }
  __syncthreads();

  // D_j[p] = (1/16) Tr(A_j sigma_p), sigma in {I,Z,Y}^4
  for (int item = tid; item < 324; item += 256) {
    const int j = item / 81, p = item % 81;
    const int p1 = p / 27, p2 = (p / 9) % 3, p3 = (p / 3) % 3, p4 = p % 3;
    int ym = 0, ny = 0;
    if (p1 == 2) { ym |= 8; ++ny; }
    if (p2 == 2) { ym |= 4; ++ny; }
    if (p3 == 2) { ym |= 2; ++ny; }
    if (p4 == 2) { ym |= 1; ++ny; }
    float sum = 0.f;
    for (int t = 0; t < 16; ++t) {
      const int t0 = (t>>3)&1, t1 = (t>>2)&1, t2 = (t>>1)&1, t3 = t&1;
      float sgn = 1.f;
      if      (p1 == 1) sgn *= t0 ? -1.f : 1.f;
      else if (p1 == 2) sgn *= t0 ?  1.f : -1.f;
      if      (p2 == 1) sgn *= t1 ? -1.f : 1.f;
      else if (p2 == 2) sgn *= t1 ?  1.f : -1.f;
      if      (p3 == 1) sgn *= t2 ? -1.f : 1.f;
      else if (p3 == 2) sgn *= t2 ?  1.f : -1.f;
      if      (p4 == 1) sgn *= t3 ? -1.f : 1.f;
      else if (p4 == 2) sgn *= t3 ?  1.f : -1.f;
      const float2 ae = A[j][t ^ ym][t];
      const int m = ny & 3;
      const float re = (m == 0) ? ae.x : (m == 1) ? -ae.y : (m == 2) ? -ae.x : ae.y;
      sum += sgn * re;
    }
    sum *= 0.0625f;
    if (p == 0) sum += bv[j];
    Dcoef[p*4 + j] = sum;
  }
}

__global__ __launch_bounds__(256) void qg_main(
    const float4* __restrict__ noise,   // [B] float4 (x0..x3)
    const float4* __restrict__ D,       // [81] float4, wave-uniform reads
    float4* __restrict__ out,           // [B] float4
    int B)
{
  const int idx = blockIdx.x * 256 + threadIdx.x;
  if (idx >= B) return;

  const float4 x = noise[idx];
  float s0,c0,s1,c1,s2,c2,s3,c3;
  __sincosf(x.x, &s0, &c0);
  __sincosf(x.y, &s1, &c1);
  __sincosf(x.z, &s2, &c2);
  __sincosf(x.w, &s3, &c3);

  // f = (1, cos, -sin); g12[a] = f1[a/3]*f2[a%3]; g34[b] = f3[b/3]*f4[b%3]
  const float g34_1 = c3,   g34_2 = -s3,
              g34_3 = c2,   g34_4 = c2*c3,  g34_5 = -c2*s3,
              g34_6 = -s2,  g34_7 = -s2*c3, g34_8 = s2*s3;
  const float g12_1 = c1,   g12_2 = -s1,
              g12_3 = c0,   g12_4 = c0*c1,  g12_5 = -c0*s1,
              g12_6 = -s0,  g12_7 = -s0*c1, g12_8 = s0*s1;

  float h0, h1, h2, h3, acc0, acc1, acc2, acc3;

#define HT(a,b,g) { const float4 q = D[(a)*9 + (b)];            \
    h0 = fmaf(q.x, (g), h0); h1 = fmaf(q.y, (g), h1);           \
    h2 = fmaf(q.z, (g), h2); h3 = fmaf(q.w, (g), h3); }
#define HB(a) { const float4 q = D[(a)*9];                      \
    h0 = q.x; h1 = q.y; h2 = q.z; h3 = q.w; }                   \
    HT(a,1,g34_1) HT(a,2,g34_2) HT(a,3,g34_3) HT(a,4,g34_4)     \
    HT(a,5,g34_5) HT(a,6,g34_6) HT(a,7,g34_7) HT(a,8,g34_8)
#define ACC(g) { acc0 = fmaf((g), h0, acc0); acc1 = fmaf((g), h1, acc1); \
                 acc2 = fmaf((g), h2, acc2); acc3 = fmaf((g), h3, acc3); }

  HB(0) acc0 = h0; acc1 = h1; acc2 = h2; acc3 = h3;
  HB(1) ACC(g12_1)
  HB(2) ACC(g12_2)
  HB(3) ACC(g12_3)
  HB(4) ACC(g12_4)
  HB(5) ACC(g12_5)
  HB(6) ACC(g12_6)
  HB(7) ACC(g12_7)
  HB(8) ACC(g12_8)

#undef HT
#undef HB
#undef ACC

  out[idx] = make_float4(fabsf(acc0) + 0.001f, acc1, acc2, acc3);
}

extern "C" void kernel_launch(void* const* d_in, const int* in_sizes, int n_in,
                              void* d_out, int out_size, void* d_ws, size_t ws_size,
                              hipStream_t stream) {
  const float* noise = (const float*)d_in[0];   // [B,4]
  const float* qw    = (const float*)d_in[1];   // [2,4,3]
  const float* Wm    = (const float*)d_in[2];   // [4,4]
  const float* bv    = (const float*)d_in[3];   // [4]
  float* Dcoef = (float*)d_ws;                  // 81*4 floats
  const int B = in_sizes[0] / 4;

  hipLaunchKernelGGL(qg_precompute, dim3(1), dim3(256), 0, stream, qw, Wm, bv, Dcoef);

  const int blocks = (B + 255) / 256;
  hipLaunchKernelGGL(qg_main, dim3(blocks), dim3(256), 0, stream,
                     (const float4*)noise, (const float4*)Dcoef, (float4*)d_out, B);
}

// Round 7
// 24.832 us; speedup vs baseline: 1.8989x; 1.0024x over previous
//
#include <hip/hip_runtime.h>
#include <math.h>

// QuantumGenerator: 4-qubit, 2-layer StronglyEntanglingLayers circuit + Linear(4,4).
// out_j(x) = sum_{p in {I,Z,Y}^4} D_j[p] * prod_w f_{p_w}(x_w),  f = (1, cos, -sin).
// qg_precompute (1 block, shfl-parallel): builds 81x4 coefficient table D in d_ws.
// qg_main (E=1): named-scalar body; D read through the CONSTANT address space as
//   scalar floats (compile-time offsets) -> s_load on the SMEM pipe, merged into
//   s_load_dwordx4+ clusters; coefficients live in SGPRs, low VGPR pressure.

__global__ __launch_bounds__(256) void qg_precompute(
    const float* __restrict__ qw,   // [2][4][3] (phi, theta, omega)
    const float* __restrict__ Wm,   // [4][4]
    const float* __restrict__ bv,   // [4]
    float* __restrict__ Dcoef)      // [81][4]
{
  __shared__ float  gm[24][8];      // per-gate 2x2 complex matrix
  __shared__ float2 Ul[16][16];     // U[k][col]
  __shared__ float  wj[4][16];
  __shared__ float2 A[4][16][16];
  const int tid = threadIdx.x;

  if (tid < 24) {
    const float phi = qw[tid*3 + 0];
    const float th  = qw[tid*3 + 1];
    const float om  = qw[tid*3 + 2];
    float st, ct, sa, ca, sd, cd;
    __sincosf(0.5f*th,       &st, &ct);
    __sincosf(0.5f*(phi+om), &sa, &ca);
    __sincosf(0.5f*(phi-om), &sd, &cd);
    gm[tid][0] =  ca*ct; gm[tid][1] = -sa*ct;   // m00
    gm[tid][2] = -cd*st; gm[tid][3] = -sd*st;   // m01
    gm[tid][4] =  cd*st; gm[tid][5] = -sd*st;   // m10
    gm[tid][6] =  ca*ct; gm[tid][7] =  sa*ct;   // m11
  }
  if (tid >= 192) {
    const int j = (tid - 192) >> 4, k = tid & 15;
    float s = 0.f;
    #pragma unroll
    for (int i = 0; i < 4; ++i)
      s += Wm[j*4 + i] * (((k >> (3 - i)) & 1) ? -1.f : 1.f);
    wj[j][k] = s;
  }
  __syncthreads();

  {  // U build: one matrix element per thread, shfl butterflies (16-lane groups)
    const int col = tid >> 4, row = tid & 15;
    float vr = (row == col) ? 1.f : 0.f, vi = 0.f;
    #pragma unroll
    for (int l = 0; l < 2; ++l) {
      #pragma unroll
      for (int w = 0; w < 4; ++w) {
        const int g = l*4 + w;
        const float m00r = gm[g][0], m00i = gm[g][1];
        const float m01r = gm[g][2], m01i = gm[g][3];
        const float m10r = gm[g][4], m10i = gm[g][5];
        const float m11r = gm[g][6], m11i = gm[g][7];
        const int mask = 8 >> w;
        const float pr = __shfl_xor(vr, mask);
        const float pi = __shfl_xor(vi, mask);
        float nr, ni;
        if (!(row & mask)) {
          nr = m00r*vr - m00i*vi + m01r*pr - m01i*pi;
          ni = m00r*vi + m00i*vr + m01r*pi + m01i*pr;
        } else {
          nr = m10r*pr - m10i*pi + m11r*vr - m11i*vi;
          ni = m10r*pi + m10i*pr + m11r*vi + m11i*vr;
        }
        vr = nr; vi = ni;
      }
      const int r = l + 1;  // StronglyEntanglingLayers ranges for 2 layers
      #pragma unroll
      for (int w = 0; w < 4; ++w) {
        const int t  = (w + r) & 3;
        const int cm = 8 >> w, tm = 8 >> t;
        const float pr = __shfl_xor(vr, tm);
        const float pi = __shfl_xor(vi, tm);
        if (row & cm) { vr = pr; vi = pi; }
      }
    }
    Ul[row][col] = make_float2(vr, vi);
  }
  __syncthreads();

  {  // A[j][s][t] = sum_k conj(U[k][s]) wj[j][k] U[k][t]
    const int s = tid >> 4, t = tid & 15;
    float ar[4] = {0,0,0,0}, ai[4] = {0,0,0,0};
    #pragma unroll
    for (int k = 0; k < 16; ++k) {
      const float2 us = Ul[k][s], ut = Ul[k][t];
      const float pr = us.x*ut.x + us.y*ut.y;
      const float pi = us.x*ut.y - us.y*ut.x;
      #pragma unroll
      for (int j = 0; j < 4; ++j) { ar[j] += wj[j][k]*pr; ai[j] += wj[j][k]*pi; }
    }
    #pragma unroll
    for (int j = 0; j < 4; ++j) A[j][s][t] = make_float2(ar[j], ai[j]);
  }
  __syncthreads();

  // D_j[p] = (1/16) Tr(A_j sigma_p), sigma in {I,Z,Y}^4
  for (int item = tid; item < 324; item += 256) {
    const int j = item / 81, p = item % 81;
    const int p1 = p / 27, p2 = (p / 9) % 3, p3 = (p / 3) % 3, p4 = p % 3;
    int ym = 0, ny = 0;
    if (p1 == 2) { ym |= 8; ++ny; }
    if (p2 == 2) { ym |= 4; ++ny; }
    if (p3 == 2) { ym |= 2; ++ny; }
    if (p4 == 2) { ym |= 1; ++ny; }
    float sum = 0.f;
    for (int t = 0; t < 16; ++t) {
      const int t0 = (t>>3)&1, t1 = (t>>2)&1, t2 = (t>>1)&1, t3 = t&1;
      float sgn = 1.f;
      if      (p1 == 1) sgn *= t0 ? -1.f : 1.f;
      else if (p1 == 2) sgn *= t0 ?  1.f : -1.f;
      if      (p2 == 1) sgn *= t1 ? -1.f : 1.f;
      else if (p2 == 2) sgn *= t1 ?  1.f : -1.f;
      if      (p3 == 1) sgn *= t2 ? -1.f : 1.f;
      else if (p3 == 2) sgn *= t2 ?  1.f : -1.f;
      if      (p4 == 1) sgn *= t3 ? -1.f : 1.f;
      else if (p4 == 2) sgn *= t3 ?  1.f : -1.f;
      const float2 ae = A[j][t ^ ym][t];
      const int m = ny & 3;
      const float re = (m == 0) ? ae.x : (m == 1) ? -ae.y : (m == 2) ? -ae.x : ae.y;
      sum += sgn * re;
    }
    sum *= 0.0625f;
    if (p == 0) sum += bv[j];
    Dcoef[p*4 + j] = sum;
  }
}

#define QG_CONST __attribute__((address_space(4)))

__global__ __launch_bounds__(256) void qg_main(
    const float4* __restrict__ noise,   // [B] float4 (x0..x3)
    const float*  __restrict__ Dg,      // [81][4] coefficient table
    float4* __restrict__ out,           // [B] float4
    int B)
{
  // Constant-AS view of D: scalar dereferences compile to s_load (SMEM pipe).
  const QG_CONST float* D = (const QG_CONST float*)(unsigned long long)Dg;

  const int idx = blockIdx.x * 256 + threadIdx.x;
  if (idx >= B) return;

  const float4 x = noise[idx];
  float s0,c0,s1,c1,s2,c2,s3,c3;
  __sincosf(x.x, &s0, &c0);
  __sincosf(x.y, &s1, &c1);
  __sincosf(x.z, &s2, &c2);
  __sincosf(x.w, &s3, &c3);

  // f = (1, cos, -sin); g12[a] = f1[a/3]*f2[a%3]; g34[b] = f3[b/3]*f4[b%3]
  const float g34_1 = c3,   g34_2 = -s3,
              g34_3 = c2,   g34_4 = c2*c3,  g34_5 = -c2*s3,
              g34_6 = -s2,  g34_7 = -s2*c3, g34_8 = s2*s3;
  const float g12_1 = c1,   g12_2 = -s1,
              g12_3 = c0,   g12_4 = c0*c1,  g12_5 = -c0*s1,
              g12_6 = -s0,  g12_7 = -s0*c1, g12_8 = s0*s1;

  float h0, h1, h2, h3, acc0, acc1, acc2, acc3;

#define HT(a,b,g) {                                                  \
    const float qx = D[((a)*9+(b))*4+0], qy = D[((a)*9+(b))*4+1];    \
    const float qz = D[((a)*9+(b))*4+2], qw_ = D[((a)*9+(b))*4+3];   \
    h0 = fmaf(qx, (g), h0); h1 = fmaf(qy, (g), h1);                  \
    h2 = fmaf(qz, (g), h2); h3 = fmaf(qw_, (g), h3); }
#define HB(a) {                                                      \
    h0 = D[(a)*36+0]; h1 = D[(a)*36+1];                              \
    h2 = D[(a)*36+2]; h3 = D[(a)*36+3]; }                            \
    HT(a,1,g34_1) HT(a,2,g34_2) HT(a,3,g34_3) HT(a,4,g34_4)          \
    HT(a,5,g34_5) HT(a,6,g34_6) HT(a,7,g34_7) HT(a,8,g34_8)
#define ACC(g) { acc0 = fmaf((g), h0, acc0); acc1 = fmaf((g), h1, acc1); \
                 acc2 = fmaf((g), h2, acc2); acc3 = fmaf((g), h3, acc3); }

  HB(0) acc0 = h0; acc1 = h1; acc2 = h2; acc3 = h3;
  HB(1) ACC(g12_1)
  HB(2) ACC(g12_2)
  HB(3) ACC(g12_3)
  HB(4) ACC(g12_4)
  HB(5) ACC(g12_5)
  HB(6) ACC(g12_6)
  HB(7) ACC(g12_7)
  HB(8) ACC(g12_8)

#undef HT
#undef HB
#undef ACC

  out[idx] = make_float4(fabsf(acc0) + 0.001f, acc1, acc2, acc3);
}

extern "C" void kernel_launch(void* const* d_in, const int* in_sizes, int n_in,
                              void* d_out, int out_size, void* d_ws, size_t ws_size,
                              hipStream_t stream) {
  const float* noise = (const float*)d_in[0];   // [B,4]
  const float* qw    = (const float*)d_in[1];   // [2,4,3]
  const float* Wm    = (const float*)d_in[2];   // [4,4]
  const float* bv    = (const float*)d_in[3];   // [4]
  float* Dcoef = (float*)d_ws;                  // 81*4 floats
  const int B = in_sizes[0] / 4;

  hipLaunchKernelGGL(qg_precompute, dim3(1), dim3(256), 0, stream, qw, Wm, bv, Dcoef);

  const int blocks = (B + 255) / 256;
  hipLaunchKernelGGL(qg_main, dim3(blocks), dim3(256), 0, stream,
                     (const float4*)noise, (const float*)Dcoef, (float4*)d_out, B);
}